// Round 5
// baseline (1004.743 us; speedup 1.0000x reference)
//
#include <hip/hip_runtime.h>

// ============================================================================
// KnowledgeGraphEncoder: 2-layer dense GAT, N=4096, H=4.
// bf16 MFMA for merged projection GEMMs (Wh+residual in one launch via B-concat);
// fp8(e4m3, per-row-max P) MFMA BK=64 for the P.Wh attention GEMMs.
// XCD-aware grids (blockIdx.x = row panel, grid.x % 8 == 0).
// ws usage ~213 MB (ws >= 230 MB proven by R3's G=4 path).
// ============================================================================

typedef unsigned short u16;
typedef unsigned char u8;
using short8  = __attribute__((ext_vector_type(8))) short;
using float4v = __attribute__((ext_vector_type(4))) float;

#define NN 4096
#define NHEADS 4

__device__ __forceinline__ u16 f2bf(float f) {
  union { float f; unsigned u; } v; v.f = f;
  unsigned u = v.u;
  return (u16)((u + 0x7FFFu + ((u >> 16) & 1u)) >> 16);   // RNE
}
__device__ __forceinline__ float bf2f(u16 x) {
  union { unsigned u; float f; } v; v.u = ((unsigned)x) << 16; return v.f;
}
// pack 4 floats -> 4 fp8 e4m3 bytes (HW cvt, OCP on gfx950)
__device__ __forceinline__ unsigned pk_fp8x4(float a, float b, float c, float d) {
  int lo = __builtin_amdgcn_cvt_pk_fp8_f32(a, b, 0, false);
  return (unsigned)__builtin_amdgcn_cvt_pk_fp8_f32(c, d, lo, true);
}

// async global->LDS, 16B per lane, LDS dest = wave-uniform base + lane*16
__device__ __forceinline__ void async16(const void* g, void* l) {
  __builtin_amdgcn_global_load_lds(
      (const __attribute__((address_space(1))) unsigned int*)g,
      (__attribute__((address_space(3))) unsigned int*)l, 16, 0, 0);
}

// ---------------------------------------------------------------- cast fp32->bf16
__global__ __launch_bounds__(256) void cast_f32_bf16(const float* __restrict__ in,
                                                     u16* __restrict__ out, int n) {
  int i = blockIdx.x * 256 + threadIdx.x;
  if (i < n) out[i] = f2bf(in[i]);
}

// ------------------------------------------------- transpose+cast fp32 -> bf16
// in [z][R][C] -> out [z][C][R]
__global__ __launch_bounds__(256) void transcast_f32(const float* __restrict__ in,
                                                     u16* __restrict__ out, int R, int C) {
  __shared__ float t[32][33];
  size_t zoff = (size_t)blockIdx.z * R * C;
  in += zoff; out += zoff;
  int c0 = blockIdx.x * 32, r0 = blockIdx.y * 32;
  int tx = threadIdx.x & 31, ty = threadIdx.x >> 5;
#pragma unroll
  for (int i = 0; i < 32; i += 8)
    t[ty + i][tx] = in[(size_t)(r0 + ty + i) * C + (c0 + tx)];
  __syncthreads();
#pragma unroll
  for (int i = 0; i < 32; i += 8)
    out[(size_t)(c0 + ty + i) * R + (r0 + tx)] = f2bf(t[tx][ty + i]);
}

// ------------------------------------------------- wa[side][h][f] = sum_o W[h][f][o]*a[h][side*O+o]
__global__ __launch_bounds__(256) void wa_kernel(const float* __restrict__ W,
                                                 const float* __restrict__ a,
                                                 float* __restrict__ wa, int F, int O) {
  int gw = blockIdx.x * 4 + (threadIdx.x >> 6);
  int lane = threadIdx.x & 63;
  int total = 2 * NHEADS * F;
  if (gw >= total) return;
  int side = gw / (NHEADS * F);
  int rem = gw - side * NHEADS * F;
  int h = rem / F, f = rem - h * F;
  const float* wrow = W + ((size_t)h * F + f) * O;
  const float* av = a + (size_t)h * 2 * O + (size_t)side * O;
  float s = 0.f;
  for (int o = lane; o < O; o += 64) s += wrow[o] * av[o];
#pragma unroll
  for (int off = 32; off > 0; off >>= 1) s += __shfl_down(s, off);
  if (lane == 0) wa[gw] = s;
}

// ------------------------------------------------- s[side][h][n] from fp32 X
__global__ __launch_bounds__(256) void s_kernel_f32(const float* __restrict__ X,
                                                    const float* __restrict__ wa,
                                                    float* __restrict__ sout, int F) {
  int gw = blockIdx.x * 4 + (threadIdx.x >> 6);
  int lane = threadIdx.x & 63;
  if (gw >= 2 * NHEADS * NN) return;
  int n = gw & (NN - 1);
  int sh = gw >> 12;
  const float* x = X + (size_t)n * F;
  const float* w = wa + (size_t)sh * F;
  float s = 0.f;
  for (int f = lane; f < F; f += 64) s += x[f] * w[f];
#pragma unroll
  for (int off = 32; off > 0; off >>= 1) s += __shfl_down(s, off);
  if (lane == 0) sout[gw] = s;
}

// ------------------------------------------------- s[side][h][n] from bf16 X
__global__ __launch_bounds__(256) void s_kernel_bf16(const u16* __restrict__ X,
                                                     const float* __restrict__ wa,
                                                     float* __restrict__ sout, int F) {
  int gw = blockIdx.x * 4 + (threadIdx.x >> 6);
  int lane = threadIdx.x & 63;
  if (gw >= 2 * NHEADS * NN) return;
  int n = gw & (NN - 1);
  int sh = gw >> 12;
  const u16* x = X + (size_t)n * F;
  const float* w = wa + (size_t)sh * F;
  float s = 0.f;
  for (int f = lane; f < F; f += 64) s += bf2f(x[f]) * w[f];
#pragma unroll
  for (int off = 32; off > 0; off >>= 1) s += __shfl_down(s, off);
  if (lane == 0) sout[gw] = s;
}

// ------------------------------------------------- G-head P' = exp(v - rowmax) fp8, l = rowsum (fp32)
// Two passes: (1) compute v -> LDS, track row max; (2) exp, pack fp8, rowsum.
template <int G>
__global__ __launch_bounds__(256) void pexp_g_kernel(const int* __restrict__ adj,
                                                     const float* __restrict__ ew,
                                                     const float* __restrict__ s,
                                                     u8* __restrict__ P,
                                                     float* __restrict__ L, int hb) {
  __shared__ float vbuf[G][NN];
  __shared__ float mred[G][4];
  __shared__ float lred[G][4];
  __shared__ float mrow[G];
  int i = blockIdx.x, tid = threadIdx.x;
  float sr[G], mx[G], lacc[G];
#pragma unroll
  for (int z = 0; z < G; z++) {
    sr[z] = s[(size_t)(hb + z) * NN + i];
    mx[z] = -3e38f;
    lacc[z] = 0.f;
  }
  const int4* arow = (const int4*)(adj + (size_t)i * NN);
  const float4* wrow = (const float4*)(ew + (size_t)i * NN);
  // pass 1: v -> LDS, row max
  for (int jv = tid; jv < NN / 4; jv += 256) {
    int4 a = arow[jv];
    float4 w = wrow[jv];
    int j0 = jv * 4;
    float we[4]; we[0] = w.x; we[1] = w.y; we[2] = w.z; we[3] = w.w;
    bool m[4];
    m[0] = (a.x != 0) || (j0 + 0 == i);
    m[1] = (a.y != 0) || (j0 + 1 == i);
    m[2] = (a.z != 0) || (j0 + 2 == i);
    m[3] = (a.w != 0) || (j0 + 3 == i);
#pragma unroll
    for (int z = 0; z < G; z++) {
      const float4 sd4 = *(const float4*)(s + (size_t)(NHEADS + hb + z) * NN + j0);
      float sd[4]; sd[0] = sd4.x; sd[1] = sd4.y; sd[2] = sd4.z; sd[3] = sd4.w;
      float4 vv;
      float* vp = (float*)&vv;
#pragma unroll
      for (int k = 0; k < 4; k++) {
        float x = sr[z] + sd[k];
        float e = x > 0.f ? x : 0.2f * x;
        float v = (m[k] ? e : -9e15f) * we[k];
        vp[k] = v;
        mx[z] = fmaxf(mx[z], v);
      }
      *(float4*)(&vbuf[z][j0]) = vv;
    }
  }
#pragma unroll
  for (int z = 0; z < G; z++) {
    float r = mx[z];
#pragma unroll
    for (int off = 32; off > 0; off >>= 1) r = fmaxf(r, __shfl_down(r, off));
    if ((tid & 63) == 0) mred[z][tid >> 6] = r;
  }
  __syncthreads();
  if (tid < G)
    mrow[tid] = fmaxf(fmaxf(mred[tid][0], mred[tid][1]), fmaxf(mred[tid][2], mred[tid][3]));
  __syncthreads();
  float mv[G];
#pragma unroll
  for (int z = 0; z < G; z++) mv[z] = mrow[z];
  // pass 2: p = exp(v - m), fp8 pack, rowsum
  for (int jv = tid; jv < NN / 4; jv += 256) {
    int j0 = jv * 4;
#pragma unroll
    for (int z = 0; z < G; z++) {
      float4 vv = *(const float4*)(&vbuf[z][j0]);
      float p0 = __expf(vv.x - mv[z]);
      float p1 = __expf(vv.y - mv[z]);
      float p2 = __expf(vv.z - mv[z]);
      float p3 = __expf(vv.w - mv[z]);
      lacc[z] += (p0 + p1) + (p2 + p3);
      *(unsigned*)(P + ((size_t)z * NN + i) * NN + j0) = pk_fp8x4(p0, p1, p2, p3);
    }
  }
#pragma unroll
  for (int z = 0; z < G; z++) {
    float r = lacc[z];
#pragma unroll
    for (int off = 32; off > 0; off >>= 1) r += __shfl_down(r, off);
    if ((tid & 63) == 0) lred[z][tid >> 6] = r;
  }
  __syncthreads();
  if (tid < G)
    L[(size_t)(hb + tid) * NN + i] = lred[tid][0] + lred[tid][1] + lred[tid][2] + lred[tid][3];
}

// ------------------------------------------------- merged projection GEMM (bf16, BK=32)
// A [4096 x K] bf16, Bt [(split + ldcF) x K] bf16 (concat of Wh heads then residual W).
// col0 <  split: fp8 TRANSPOSED store into F8T[gcol][0..4095]   (Wh^T, packed dword)
// col0 >= split: fp32 store F32[grow][gcol-split] = v + bias[gcol-split]
// Grid: (x = 32 row panels, y = (split+ldcF)/128 col panels). XCD: same-A -> same XCD.
__global__ __launch_bounds__(256) void gemm_proj(const u16* __restrict__ A,
                                                 const u16* __restrict__ Bt,
                                                 u8* __restrict__ F8T,
                                                 float* __restrict__ F32,
                                                 const float* __restrict__ bias,
                                                 int K, int split, int ldcF) {
  int row0 = blockIdx.x * 128;
  int col0 = blockIdx.y * 128;

  __shared__ u16 ldsA[128 * 32];
  __shared__ u16 ldsB[128 * 32];

  int tid = threadIdx.x;
  int wave = tid >> 6, lane = tid & 63;
  int wm = wave >> 1, wn = wave & 1;
  int lm = lane & 15, kq = (lane >> 4) * 8;

  const u16* aPtr = A  + (size_t)(row0 + (tid >> 2)) * K + ((tid & 3) * 8);
  const u16* bPtr = Bt + (size_t)(col0 + (tid >> 2)) * K + ((tid & 3) * 8);
  u16* ldsAw = &ldsA[wave * 512];
  u16* ldsBw = &ldsB[wave * 512];
  const size_t rowStep = (size_t)64 * K;

  float4v acc[4][4] = {};

  for (int k0 = 0; k0 < K; k0 += 32) {
    __syncthreads();
    async16(aPtr + k0,           ldsAw);
    async16(aPtr + k0 + rowStep, ldsAw + 2048);
    async16(bPtr + k0,           ldsBw);
    async16(bPtr + k0 + rowStep, ldsBw + 2048);
    __syncthreads();
    short8 af[4], bf[4];
#pragma unroll
    for (int s = 0; s < 4; s++) {
      af[s] = *(const short8*)(&ldsA[(wm * 64 + s * 16 + lm) * 32 + kq]);
      bf[s] = *(const short8*)(&ldsB[(wn * 64 + s * 16 + lm) * 32 + kq]);
    }
#pragma unroll
    for (int i = 0; i < 4; i++)
#pragma unroll
      for (int j = 0; j < 4; j++)
        acc[i][j] = __builtin_amdgcn_mfma_f32_16x16x32_bf16(af[i], bf[j], acc[i][j], 0, 0, 0);
  }

  if (col0 < split) {
#pragma unroll
    for (int i = 0; i < 4; i++) {
#pragma unroll
      for (int j = 0; j < 4; j++) {
        int grow0 = row0 + wm * 64 + i * 16 + (lane >> 4) * 4;
        int gcol = col0 + wn * 64 + j * 16 + lm;
        unsigned pk = pk_fp8x4(acc[i][j][0], acc[i][j][1], acc[i][j][2], acc[i][j][3]);
        *(unsigned*)&F8T[(size_t)gcol * NN + grow0] = pk;
      }
    }
  } else {
#pragma unroll
    for (int i = 0; i < 4; i++) {
#pragma unroll
      for (int j = 0; j < 4; j++) {
#pragma unroll
        for (int r = 0; r < 4; r++) {
          int grow = row0 + wm * 64 + i * 16 + (lane >> 4) * 4 + r;
          int gcol = col0 + wn * 64 + j * 16 + lm - split;
          F32[(size_t)grow * ldcF + gcol] = acc[i][j][r] + bias[gcol];
        }
      }
    }
  }
}

// ------------------------------------------------- 128x128 fp8 MFMA GEMM, BK=64, B^T input, K=NN
// MODE 2: C[grow*ldc + coloff+gcol] += elu(v / l[row])   (layer-0 attn, disjoint head cols)
// MODE 3: C[h*cStride + grow*ldc + gcol] = v / l[row]    (layer-1 attn, per-head plain store)
// Grid: (x = 32 row panels, y = col panels, z = heads in group).
template <int MODE>
__global__ __launch_bounds__(256) void gemm_fp8(const u8* __restrict__ A,
                                                const u8* __restrict__ Bt,
                                                float* __restrict__ Cout,
                                                const float* __restrict__ rowscale,
                                                int ldc, int coloff_base, int coloff_step,
                                                size_t bStride, size_t cStride) {
  constexpr int K = NN;
  int h = blockIdx.z;
  const u8* Ab = A + (size_t)h * ((size_t)NN * NN);
  const u8* Bb = Bt + (size_t)h * bStride;
  const float* rs = rowscale + (size_t)h * NN;
  int row0 = blockIdx.x * 128;
  int col0 = blockIdx.y * 128;
  int coloff = coloff_base + h * coloff_step;

  __shared__ u8 ldsA[128 * 64];
  __shared__ u8 ldsB[128 * 64];

  int tid = threadIdx.x;
  int wave = tid >> 6, lane = tid & 63;
  int wm = wave >> 1, wn = wave & 1;
  int lm = lane & 15, kq8 = (lane >> 4) * 8;

  const u8* aPtr = Ab + (size_t)(row0 + (tid >> 2)) * K + ((tid & 3) * 16);
  const u8* bPtr = Bb + (size_t)(col0 + (tid >> 2)) * K + ((tid & 3) * 16);
  u8* ldsAw = &ldsA[wave * 1024];
  u8* ldsBw = &ldsB[wave * 1024];
  const size_t rowStep = (size_t)64 * K;

  float4v acc[4][4] = {};

  for (int k0 = 0; k0 < K; k0 += 64) {
    __syncthreads();
    async16(aPtr + k0,           ldsAw);           // rows 0-63
    async16(aPtr + k0 + rowStep, ldsAw + 4096);    // rows 64-127
    async16(bPtr + k0,           ldsBw);
    async16(bPtr + k0 + rowStep, ldsBw + 4096);
    __syncthreads();
    long a8[4][2], b8[4][2];
#pragma unroll
    for (int s = 0; s < 4; s++) {
#pragma unroll
      for (int kb = 0; kb < 2; kb++) {
        a8[s][kb] = *(const long*)(&ldsA[(wm * 64 + s * 16 + lm) * 64 + kb * 32 + kq8]);
        b8[s][kb] = *(const long*)(&ldsB[(wn * 64 + s * 16 + lm) * 64 + kb * 32 + kq8]);
      }
    }
#pragma unroll
    for (int i = 0; i < 4; i++)
#pragma unroll
      for (int j = 0; j < 4; j++) {
        acc[i][j] = __builtin_amdgcn_mfma_f32_16x16x32_fp8_fp8(a8[i][0], b8[j][0], acc[i][j], 0, 0, 0);
        acc[i][j] = __builtin_amdgcn_mfma_f32_16x16x32_fp8_fp8(a8[i][1], b8[j][1], acc[i][j], 0, 0, 0);
      }
  }

#pragma unroll
  for (int i = 0; i < 4; i++) {
#pragma unroll
    for (int j = 0; j < 4; j++) {
#pragma unroll
      for (int r = 0; r < 4; r++) {
        int grow = row0 + wm * 64 + i * 16 + (lane >> 4) * 4 + r;
        int gcol = col0 + wn * 64 + j * 16 + lm;
        float v = acc[i][j][r] * (1.0f / rs[grow]);
        if constexpr (MODE == 2) {
          size_t idx = (size_t)grow * ldc + coloff + gcol;
          v = v > 0.f ? v : (__expf(v) - 1.f);
          Cout[idx] += v;
        } else {
          Cout[(size_t)h * cStride + (size_t)grow * ldc + gcol] = v;
        }
      }
    }
  }
}

// ------------------------------------------------- LN layer 0: LN(x) -> elu -> bf16
__global__ __launch_bounds__(256) void ln0_kernel(const float* __restrict__ xin,
                                                  const float* __restrict__ g,
                                                  const float* __restrict__ b,
                                                  u16* __restrict__ h1b) {
  const int C = 2048;
  int n = blockIdx.x, tid = threadIdx.x;
  __shared__ float red[2][4];
  __shared__ float mrs[2];
  float sum = 0.f, sq = 0.f;
  const float* xr = xin + (size_t)n * C;
  for (int c = tid; c < C; c += 256) {
    float x = xr[c];
    sum += x; sq += x * x;
  }
#pragma unroll
  for (int off = 32; off > 0; off >>= 1) { sum += __shfl_down(sum, off); sq += __shfl_down(sq, off); }
  if ((tid & 63) == 0) { red[0][tid >> 6] = sum; red[1][tid >> 6] = sq; }
  __syncthreads();
  if (tid == 0) {
    float s = red[0][0] + red[0][1] + red[0][2] + red[0][3];
    float q = red[1][0] + red[1][1] + red[1][2] + red[1][3];
    float mean = s / C, var = q / C - mean * mean;
    mrs[0] = mean; mrs[1] = rsqrtf(var + 1e-5f);
  }
  __syncthreads();
  float mean = mrs[0], rstd = mrs[1];
  for (int c = tid; c < C; c += 256) {
    float y = (xr[c] - mean) * rstd * g[c] + b[c];
    float z = y > 0.f ? y : (__expf(y) - 1.f);
    h1b[(size_t)n * C + c] = f2bf(z);
  }
}

// ------------------------------------------------- LN layer 1: mean(4 heads) + rp1 -> LN -> out
__global__ __launch_bounds__(256) void ln1_kernel(const float* __restrict__ hp1,
                                                  const float* __restrict__ rp1,
                                                  const float* __restrict__ g,
                                                  const float* __restrict__ b,
                                                  float* __restrict__ out) {
  const int C = 768;
  int n = blockIdx.x, tid = threadIdx.x;
  __shared__ float xs[768];
  __shared__ float red[2][4];
  __shared__ float mrs[2];
  float sum = 0.f, sq = 0.f;
  for (int c = tid; c < C; c += 256) {
    float x = 0.25f * (hp1[((size_t)0 * NN + n) * C + c] + hp1[((size_t)1 * NN + n) * C + c] +
                       hp1[((size_t)2 * NN + n) * C + c] + hp1[((size_t)3 * NN + n) * C + c]);
    x += rp1[(size_t)n * C + c];     // bias already folded into rp1 by gemm_proj
    xs[c] = x; sum += x; sq += x * x;
  }
#pragma unroll
  for (int off = 32; off > 0; off >>= 1) { sum += __shfl_down(sum, off); sq += __shfl_down(sq, off); }
  if ((tid & 63) == 0) { red[0][tid >> 6] = sum; red[1][tid >> 6] = sq; }
  __syncthreads();
  if (tid == 0) {
    float s = red[0][0] + red[0][1] + red[0][2] + red[0][3];
    float q = red[1][0] + red[1][1] + red[1][2] + red[1][3];
    float mean = s / C, var = q / C - mean * mean;
    mrs[0] = mean; mrs[1] = rsqrtf(var + 1e-5f);
  }
  __syncthreads();
  float mean = mrs[0], rstd = mrs[1];
  for (int c = tid; c < C; c += 256)
    out[(size_t)n * C + c] = (xs[c] - mean) * rstd * g[c] + b[c];
}

// ============================================================================
extern "C" void kernel_launch(void* const* d_in, const int* in_sizes, int n_in,
                              void* d_out, int out_size, void* d_ws, size_t ws_size,
                              hipStream_t stream) {
  (void)in_sizes; (void)n_in; (void)out_size;
  const float* X    = (const float*)d_in[0];
  const int*   adj  = (const int*)d_in[1];
  const float* ew   = (const float*)d_in[2];
  const float* W0   = (const float*)d_in[3];
  const float* a0   = (const float*)d_in[4];
  const float* W1   = (const float*)d_in[5];
  const float* a1   = (const float*)d_in[6];
  const float* rp0w = (const float*)d_in[7];
  const float* rp0b = (const float*)d_in[8];
  const float* rp1w = (const float*)d_in[9];
  const float* rp1b = (const float*)d_in[10];
  const float* ln0g = (const float*)d_in[11];
  const float* ln0b = (const float*)d_in[12];
  const float* ln1g = (const float*)d_in[13];
  const float* ln1b = (const float*)d_in[14];
  float* out = (float*)d_out;
  char* wsb = (char*)d_ws;

  // ---- workspace layout (bytes) ----
  // NOTE: W0T/RP0WT contiguous and W1T/RP1WT contiguous (B-concat for gemm_proj).
  constexpr size_t OFF_XBF   = 0;             // [4096][768]    bf16   6291456
  constexpr size_t OFF_W0T   = 6291456;       // [2048][768]    bf16   3145728  (4 heads x 512)
  constexpr size_t OFF_RP0WT = 9437184;       // [2048][768]    bf16   3145728  (contiguous after W0T)
  constexpr size_t OFF_W1T   = 12582912;      // [3072][2048]   bf16  12582912  (4 heads x 768)
  constexpr size_t OFF_RP1WT = 25165824;      // [768][2048]    bf16   3145728  (contiguous after W1T)
  constexpr size_t OFF_WA0   = 28311552;
  constexpr size_t OFF_WA1   = 28336128;
  constexpr size_t OFF_S0    = 28401664;
  constexpr size_t OFF_S1    = 28532736;
  constexpr size_t OFF_L0    = 28664320;
  constexpr size_t OFF_L1    = 28729856;
  constexpr size_t OFF_H1B   = 28795392;      // [4096][2048] bf16   16777216
  constexpr size_t D         = 45572608;      // dynamic region
  // layer0: WH0T [2048][4096] fp8 @D (8388608);  RP0 [4096][2048] f32 @D+16777216 (33554432)
  // layer1: WH1T [3072][4096] fp8 @D (12582912); RP1 [4096][768]  f32 @D+25165824 (12582912)
  constexpr size_t PD        = D + 50331648;          // P @ 95904256, 4 x 16777216 fp8
  constexpr size_t PN        = (size_t)NN * NN;       // 16777216 per head
  constexpr size_t OFF_HP1   = PD + 4 * PN;           // [4][4096][768] f32 @163013120 -> ends 213344768

  u16*   XBF   = (u16*)(wsb + OFF_XBF);
  u16*   W0T   = (u16*)(wsb + OFF_W0T);
  u16*   RP0WT = (u16*)(wsb + OFF_RP0WT);
  u16*   W1T   = (u16*)(wsb + OFF_W1T);
  u16*   RP1WT = (u16*)(wsb + OFF_RP1WT);
  float* WA0   = (float*)(wsb + OFF_WA0);
  float* WA1   = (float*)(wsb + OFF_WA1);
  float* S0    = (float*)(wsb + OFF_S0);
  float* S1    = (float*)(wsb + OFF_S1);
  float* L0    = (float*)(wsb + OFF_L0);
  float* L1    = (float*)(wsb + OFF_L1);
  u16*   H1B   = (u16*)(wsb + OFF_H1B);
  u8*    WH0T  = (u8*)(wsb + D);
  float* RP0   = (float*)(wsb + D + 16777216);
  u8*    WH1T  = (u8*)(wsb + D);
  float* RP1   = (float*)(wsb + D + 25165824);
  u8*    P     = (u8*)(wsb + PD);
  float* HP1   = (float*)(wsb + OFF_HP1);

  // head-group size from available workspace (ws_size constant per session).
  // R3 ran G=4 at need 230,121,984 -> ws proven >= that; here G=4 needs 213,344,768.
  const int G = (ws_size >= OFF_HP1 + 50331648) ? 4 : 1;

  // ---- prep ----
  cast_f32_bf16<<<dim3((NN * 768 + 255) / 256), 256, 0, stream>>>(X, XBF, NN * 768);
  transcast_f32<<<dim3(16, 24, 4), 256, 0, stream>>>(W0, W0T, 768, 512);
  transcast_f32<<<dim3(24, 64, 4), 256, 0, stream>>>(W1, W1T, 2048, 768);
  transcast_f32<<<dim3(64, 24, 1), 256, 0, stream>>>(rp0w, RP0WT, 768, 2048);
  transcast_f32<<<dim3(24, 64, 1), 256, 0, stream>>>(rp1w, RP1WT, 2048, 768);

  // ---- layer 0 attention scalars (fp32 exact) ----
  wa_kernel<<<dim3(2 * NHEADS * 768 / 4), 256, 0, stream>>>(W0, a0, WA0, 768, 512);
  s_kernel_f32<<<dim3(2 * NHEADS * NN / 4), 256, 0, stream>>>(X, WA0, S0, 768);

  // ---- layer 0: merged projections (Wh0^T fp8 + RP0 fp32+bias), one launch ----
  gemm_proj<<<dim3(32, 32), 256, 0, stream>>>(XBF, W0T, WH0T, RP0, rp0b, 768, 2048, 2048);

  // per head-group: P' then RP0[:, h*512:(h+1)*512] += elu(P' @ Wh0 / l)
  for (int g = 0; g < NHEADS; g += G) {
    if (G == 4) pexp_g_kernel<4><<<dim3(NN), 256, 0, stream>>>(adj, ew, S0, P, L0, g);
    else        pexp_g_kernel<1><<<dim3(NN), 256, 0, stream>>>(adj, ew, S0, P, L0, g);
    gemm_fp8<2><<<dim3(32, 4, G), 256, 0, stream>>>(P, WH0T + (size_t)g * 512 * NN,
        RP0, L0 + (size_t)g * NN, 2048, g * 512, 512, (size_t)512 * NN, 0);
  }
  ln0_kernel<<<dim3(NN), 256, 0, stream>>>(RP0, ln0g, ln0b, H1B);

  // ---- layer 1 attention scalars ----
  wa_kernel<<<dim3(2 * NHEADS * 2048 / 4), 256, 0, stream>>>(W1, a1, WA1, 2048, 768);
  s_kernel_bf16<<<dim3(2 * NHEADS * NN / 4), 256, 0, stream>>>(H1B, WA1, S1, 2048);

  // ---- layer 1: merged projections (Wh1^T fp8 + RP1 fp32+bias), one launch ----
  gemm_proj<<<dim3(32, 30), 256, 0, stream>>>(H1B, W1T, WH1T, RP1, rp1b, 2048, 3072, 768);

  // per head-group: P' then HP1[h] = P' @ Wh1 / l (plain store; ln1 does mean)
  for (int g = 0; g < NHEADS; g += G) {
    if (G == 4) pexp_g_kernel<4><<<dim3(NN), 256, 0, stream>>>(adj, ew, S1, P, L1, g);
    else        pexp_g_kernel<1><<<dim3(NN), 256, 0, stream>>>(adj, ew, S1, P, L1, g);
    gemm_fp8<3><<<dim3(32, 6, G), 256, 0, stream>>>(P, WH1T + (size_t)g * 768 * NN,
        HP1 + (size_t)g * NN * 768, L1 + (size_t)g * NN,
        768, 0, 0, (size_t)768 * NN, (size_t)NN * 768);
  }
  ln1_kernel<<<dim3(NN), 256, 0, stream>>>(HP1, RP1, ln1g, ln1b, out);
}

// Round 6
// 810.057 us; speedup vs baseline: 1.2403x; 1.2403x over previous
//
#include <hip/hip_runtime.h>

// ============================================================================
// KnowledgeGraphEncoder: 2-layer dense GAT, N=4096, H=4.
// bf16 MFMA for merged projection GEMMs (Wh+residual in one launch via B-concat);
// fp8(e4m3, per-row-max P) MFMA BK=64 for the P.Wh attention GEMMs,
// ds_read_b128 fragment loads via K-permutation (conflict-free LDS).
// XCD-aware grids (blockIdx.x = row panel, grid.x % 8 == 0).
// ws usage ~213 MB (ws >= 230 MB proven by R3's G=4 path).
// ============================================================================

typedef unsigned short u16;
typedef unsigned char u8;
using short8  = __attribute__((ext_vector_type(8))) short;
using float4v = __attribute__((ext_vector_type(4))) float;
using long2v  = __attribute__((ext_vector_type(2))) long;

#define NN 4096
#define NHEADS 4

__device__ __forceinline__ u16 f2bf(float f) {
  union { float f; unsigned u; } v; v.f = f;
  unsigned u = v.u;
  return (u16)((u + 0x7FFFu + ((u >> 16) & 1u)) >> 16);   // RNE
}
__device__ __forceinline__ float bf2f(u16 x) {
  union { unsigned u; float f; } v; v.u = ((unsigned)x) << 16; return v.f;
}
// pack 4 floats -> 4 fp8 e4m3 bytes (HW cvt, OCP on gfx950)
__device__ __forceinline__ unsigned pk_fp8x4(float a, float b, float c, float d) {
  int lo = __builtin_amdgcn_cvt_pk_fp8_f32(a, b, 0, false);
  return (unsigned)__builtin_amdgcn_cvt_pk_fp8_f32(c, d, lo, true);
}

// async global->LDS, 16B per lane, LDS dest = wave-uniform base + lane*16
__device__ __forceinline__ void async16(const void* g, void* l) {
  __builtin_amdgcn_global_load_lds(
      (const __attribute__((address_space(1))) unsigned int*)g,
      (__attribute__((address_space(3))) unsigned int*)l, 16, 0, 0);
}

// ---------------------------------------------------------------- cast fp32->bf16
__global__ __launch_bounds__(256) void cast_f32_bf16(const float* __restrict__ in,
                                                     u16* __restrict__ out, int n) {
  int i = blockIdx.x * 256 + threadIdx.x;
  if (i < n) out[i] = f2bf(in[i]);
}

// ------------------------------------------------- transpose+cast fp32 -> bf16
// in [z][R][C] -> out [z][C][R]
__global__ __launch_bounds__(256) void transcast_f32(const float* __restrict__ in,
                                                     u16* __restrict__ out, int R, int C) {
  __shared__ float t[32][33];
  size_t zoff = (size_t)blockIdx.z * R * C;
  in += zoff; out += zoff;
  int c0 = blockIdx.x * 32, r0 = blockIdx.y * 32;
  int tx = threadIdx.x & 31, ty = threadIdx.x >> 5;
#pragma unroll
  for (int i = 0; i < 32; i += 8)
    t[ty + i][tx] = in[(size_t)(r0 + ty + i) * C + (c0 + tx)];
  __syncthreads();
#pragma unroll
  for (int i = 0; i < 32; i += 8)
    out[(size_t)(c0 + ty + i) * R + (r0 + tx)] = f2bf(t[tx][ty + i]);
}

// ------------------------------------------------- wa[side][h][f] = sum_o W[h][f][o]*a[h][side*O+o]
__global__ __launch_bounds__(256) void wa_kernel(const float* __restrict__ W,
                                                 const float* __restrict__ a,
                                                 float* __restrict__ wa, int F, int O) {
  int gw = blockIdx.x * 4 + (threadIdx.x >> 6);
  int lane = threadIdx.x & 63;
  int total = 2 * NHEADS * F;
  if (gw >= total) return;
  int side = gw / (NHEADS * F);
  int rem = gw - side * NHEADS * F;
  int h = rem / F, f = rem - h * F;
  const float* wrow = W + ((size_t)h * F + f) * O;
  const float* av = a + (size_t)h * 2 * O + (size_t)side * O;
  float s = 0.f;
  for (int o = lane; o < O; o += 64) s += wrow[o] * av[o];
#pragma unroll
  for (int off = 32; off > 0; off >>= 1) s += __shfl_down(s, off);
  if (lane == 0) wa[gw] = s;
}

// ------------------------------------------------- s[side][h][n] from fp32 X
__global__ __launch_bounds__(256) void s_kernel_f32(const float* __restrict__ X,
                                                    const float* __restrict__ wa,
                                                    float* __restrict__ sout, int F) {
  int gw = blockIdx.x * 4 + (threadIdx.x >> 6);
  int lane = threadIdx.x & 63;
  if (gw >= 2 * NHEADS * NN) return;
  int n = gw & (NN - 1);
  int sh = gw >> 12;
  const float* x = X + (size_t)n * F;
  const float* w = wa + (size_t)sh * F;
  float s = 0.f;
  for (int f = lane; f < F; f += 64) s += x[f] * w[f];
#pragma unroll
  for (int off = 32; off > 0; off >>= 1) s += __shfl_down(s, off);
  if (lane == 0) sout[gw] = s;
}

// ------------------------------------------------- s[side][h][n] from bf16 X
__global__ __launch_bounds__(256) void s_kernel_bf16(const u16* __restrict__ X,
                                                     const float* __restrict__ wa,
                                                     float* __restrict__ sout, int F) {
  int gw = blockIdx.x * 4 + (threadIdx.x >> 6);
  int lane = threadIdx.x & 63;
  if (gw >= 2 * NHEADS * NN) return;
  int n = gw & (NN - 1);
  int sh = gw >> 12;
  const u16* x = X + (size_t)n * F;
  const float* w = wa + (size_t)sh * F;
  float s = 0.f;
  for (int f = lane; f < F; f += 64) s += bf2f(x[f]) * w[f];
#pragma unroll
  for (int off = 32; off > 0; off >>= 1) s += __shfl_down(s, off);
  if (lane == 0) sout[gw] = s;
}

// ------------------------------------------------- G-head P' = exp(v - rowmax) fp8, l = rowsum (fp32)
// Two passes: (1) compute v -> LDS, track row max; (2) exp, pack fp8, rowsum.
template <int G>
__global__ __launch_bounds__(256) void pexp_g_kernel(const int* __restrict__ adj,
                                                     const float* __restrict__ ew,
                                                     const float* __restrict__ s,
                                                     u8* __restrict__ P,
                                                     float* __restrict__ L, int hb) {
  __shared__ float vbuf[G][NN];
  __shared__ float mred[G][4];
  __shared__ float lred[G][4];
  __shared__ float mrow[G];
  int i = blockIdx.x, tid = threadIdx.x;
  float sr[G], mx[G], lacc[G];
#pragma unroll
  for (int z = 0; z < G; z++) {
    sr[z] = s[(size_t)(hb + z) * NN + i];
    mx[z] = -3e38f;
    lacc[z] = 0.f;
  }
  const int4* arow = (const int4*)(adj + (size_t)i * NN);
  const float4* wrow = (const float4*)(ew + (size_t)i * NN);
  // pass 1: v -> LDS, row max
  for (int jv = tid; jv < NN / 4; jv += 256) {
    int4 a = arow[jv];
    float4 w = wrow[jv];
    int j0 = jv * 4;
    float we[4]; we[0] = w.x; we[1] = w.y; we[2] = w.z; we[3] = w.w;
    bool m[4];
    m[0] = (a.x != 0) || (j0 + 0 == i);
    m[1] = (a.y != 0) || (j0 + 1 == i);
    m[2] = (a.z != 0) || (j0 + 2 == i);
    m[3] = (a.w != 0) || (j0 + 3 == i);
#pragma unroll
    for (int z = 0; z < G; z++) {
      const float4 sd4 = *(const float4*)(s + (size_t)(NHEADS + hb + z) * NN + j0);
      float sd[4]; sd[0] = sd4.x; sd[1] = sd4.y; sd[2] = sd4.z; sd[3] = sd4.w;
      float4 vv;
      float* vp = (float*)&vv;
#pragma unroll
      for (int k = 0; k < 4; k++) {
        float x = sr[z] + sd[k];
        float e = x > 0.f ? x : 0.2f * x;
        float v = (m[k] ? e : -9e15f) * we[k];
        vp[k] = v;
        mx[z] = fmaxf(mx[z], v);
      }
      *(float4*)(&vbuf[z][j0]) = vv;
    }
  }
#pragma unroll
  for (int z = 0; z < G; z++) {
    float r = mx[z];
#pragma unroll
    for (int off = 32; off > 0; off >>= 1) r = fmaxf(r, __shfl_down(r, off));
    if ((tid & 63) == 0) mred[z][tid >> 6] = r;
  }
  __syncthreads();
  if (tid < G)
    mrow[tid] = fmaxf(fmaxf(mred[tid][0], mred[tid][1]), fmaxf(mred[tid][2], mred[tid][3]));
  __syncthreads();
  float mv[G];
#pragma unroll
  for (int z = 0; z < G; z++) mv[z] = mrow[z];
  // pass 2: p = exp(v - m), fp8 pack, rowsum
  for (int jv = tid; jv < NN / 4; jv += 256) {
    int j0 = jv * 4;
#pragma unroll
    for (int z = 0; z < G; z++) {
      float4 vv = *(const float4*)(&vbuf[z][j0]);
      float p0 = __expf(vv.x - mv[z]);
      float p1 = __expf(vv.y - mv[z]);
      float p2 = __expf(vv.z - mv[z]);
      float p3 = __expf(vv.w - mv[z]);
      lacc[z] += (p0 + p1) + (p2 + p3);
      *(unsigned*)(P + ((size_t)z * NN + i) * NN + j0) = pk_fp8x4(p0, p1, p2, p3);
    }
  }
#pragma unroll
  for (int z = 0; z < G; z++) {
    float r = lacc[z];
#pragma unroll
    for (int off = 32; off > 0; off >>= 1) r += __shfl_down(r, off);
    if ((tid & 63) == 0) lred[z][tid >> 6] = r;
  }
  __syncthreads();
  if (tid < G)
    L[(size_t)(hb + tid) * NN + i] = lred[tid][0] + lred[tid][1] + lred[tid][2] + lred[tid][3];
}

// ------------------------------------------------- merged projection GEMM (bf16, BK=32)
// A [4096 x K] bf16, Bt [(split + ldcF) x K] bf16 (concat of Wh heads then residual W).
// col0 <  split: fp8 TRANSPOSED store into F8T[gcol][0..4095]   (Wh^T, packed dword)
// col0 >= split: fp32 store F32[grow][gcol-split] = v + bias[gcol-split]
// Grid: (x = 32 row panels, y = col panels). XCD: same-A -> same XCD.
__global__ __launch_bounds__(256) void gemm_proj(const u16* __restrict__ A,
                                                 const u16* __restrict__ Bt,
                                                 u8* __restrict__ F8T,
                                                 float* __restrict__ F32,
                                                 const float* __restrict__ bias,
                                                 int K, int split, int ldcF) {
  int row0 = blockIdx.x * 128;
  int col0 = blockIdx.y * 128;

  __shared__ u16 ldsA[128 * 32];
  __shared__ u16 ldsB[128 * 32];

  int tid = threadIdx.x;
  int wave = tid >> 6, lane = tid & 63;
  int wm = wave >> 1, wn = wave & 1;
  int lm = lane & 15, kq = (lane >> 4) * 8;

  const u16* aPtr = A  + (size_t)(row0 + (tid >> 2)) * K + ((tid & 3) * 8);
  const u16* bPtr = Bt + (size_t)(col0 + (tid >> 2)) * K + ((tid & 3) * 8);
  u16* ldsAw = &ldsA[wave * 512];
  u16* ldsBw = &ldsB[wave * 512];
  const size_t rowStep = (size_t)64 * K;

  float4v acc[4][4] = {};

  for (int k0 = 0; k0 < K; k0 += 32) {
    __syncthreads();
    async16(aPtr + k0,           ldsAw);
    async16(aPtr + k0 + rowStep, ldsAw + 2048);
    async16(bPtr + k0,           ldsBw);
    async16(bPtr + k0 + rowStep, ldsBw + 2048);
    __syncthreads();
    short8 af[4], bf[4];
#pragma unroll
    for (int s = 0; s < 4; s++) {
      af[s] = *(const short8*)(&ldsA[(wm * 64 + s * 16 + lm) * 32 + kq]);
      bf[s] = *(const short8*)(&ldsB[(wn * 64 + s * 16 + lm) * 32 + kq]);
    }
#pragma unroll
    for (int i = 0; i < 4; i++)
#pragma unroll
      for (int j = 0; j < 4; j++)
        acc[i][j] = __builtin_amdgcn_mfma_f32_16x16x32_bf16(af[i], bf[j], acc[i][j], 0, 0, 0);
  }

  if (col0 < split) {
#pragma unroll
    for (int i = 0; i < 4; i++) {
#pragma unroll
      for (int j = 0; j < 4; j++) {
        int grow0 = row0 + wm * 64 + i * 16 + (lane >> 4) * 4;
        int gcol = col0 + wn * 64 + j * 16 + lm;
        unsigned pk = pk_fp8x4(acc[i][j][0], acc[i][j][1], acc[i][j][2], acc[i][j][3]);
        *(unsigned*)&F8T[(size_t)gcol * NN + grow0] = pk;
      }
    }
  } else {
#pragma unroll
    for (int i = 0; i < 4; i++) {
#pragma unroll
      for (int j = 0; j < 4; j++) {
#pragma unroll
        for (int r = 0; r < 4; r++) {
          int grow = row0 + wm * 64 + i * 16 + (lane >> 4) * 4 + r;
          int gcol = col0 + wn * 64 + j * 16 + lm - split;
          F32[(size_t)grow * ldcF + gcol] = acc[i][j][r] + bias[gcol];
        }
      }
    }
  }
}

// ------------------------------------------------- 128x128 fp8 MFMA GEMM, BK=64, B^T input, K=NN
// Fragment loads are ds_read_b128 at row*64 + quad*16; the two 8B halves feed
// two MFMAs. This permutes MFMA K-order (identically for A and B) -> correct,
// and gives the conflict-free b128 bank pattern.
// MODE 2: C[grow*ldc + coloff+gcol] += elu(v / l[row])   (layer-0 attn, disjoint head cols)
// MODE 3: C[h*cStride + grow*ldc + gcol] = v / l[row]    (layer-1 attn, per-head plain store)
// Grid: (x = 32 row panels, y = col panels, z = heads in group).
template <int MODE>
__global__ __launch_bounds__(256) void gemm_fp8(const u8* __restrict__ A,
                                                const u8* __restrict__ Bt,
                                                float* __restrict__ Cout,
                                                const float* __restrict__ rowscale,
                                                int ldc, int coloff_base, int coloff_step,
                                                size_t bStride, size_t cStride) {
  constexpr int K = NN;
  int h = blockIdx.z;
  const u8* Ab = A + (size_t)h * ((size_t)NN * NN);
  const u8* Bb = Bt + (size_t)h * bStride;
  const float* rs = rowscale + (size_t)h * NN;
  int row0 = blockIdx.x * 128;
  int col0 = blockIdx.y * 128;
  int coloff = coloff_base + h * coloff_step;

  __shared__ u8 ldsA[128 * 64];
  __shared__ u8 ldsB[128 * 64];

  int tid = threadIdx.x;
  int wave = tid >> 6, lane = tid & 63;
  int wm = wave >> 1, wn = wave & 1;
  int lm = lane & 15, q16 = (lane >> 4) * 16;

  const u8* aPtr = Ab + (size_t)(row0 + (tid >> 2)) * K + ((tid & 3) * 16);
  const u8* bPtr = Bb + (size_t)(col0 + (tid >> 2)) * K + ((tid & 3) * 16);
  u8* ldsAw = &ldsA[wave * 1024];
  u8* ldsBw = &ldsB[wave * 1024];
  const size_t rowStep = (size_t)64 * K;

  float4v acc[4][4] = {};

  for (int k0 = 0; k0 < K; k0 += 64) {
    __syncthreads();
    async16(aPtr + k0,           ldsAw);           // rows 0-63
    async16(aPtr + k0 + rowStep, ldsAw + 4096);    // rows 64-127
    async16(bPtr + k0,           ldsBw);
    async16(bPtr + k0 + rowStep, ldsBw + 4096);
    __syncthreads();
    long2v a16[4], b16[4];
#pragma unroll
    for (int s = 0; s < 4; s++) {
      a16[s] = *(const long2v*)(&ldsA[(wm * 64 + s * 16 + lm) * 64 + q16]);
      b16[s] = *(const long2v*)(&ldsB[(wn * 64 + s * 16 + lm) * 64 + q16]);
    }
#pragma unroll
    for (int i = 0; i < 4; i++)
#pragma unroll
      for (int j = 0; j < 4; j++) {
        acc[i][j] = __builtin_amdgcn_mfma_f32_16x16x32_fp8_fp8(a16[i][0], b16[j][0], acc[i][j], 0, 0, 0);
        acc[i][j] = __builtin_amdgcn_mfma_f32_16x16x32_fp8_fp8(a16[i][1], b16[j][1], acc[i][j], 0, 0, 0);
      }
  }

#pragma unroll
  for (int i = 0; i < 4; i++) {
#pragma unroll
    for (int j = 0; j < 4; j++) {
#pragma unroll
      for (int r = 0; r < 4; r++) {
        int grow = row0 + wm * 64 + i * 16 + (lane >> 4) * 4 + r;
        int gcol = col0 + wn * 64 + j * 16 + lm;
        float v = acc[i][j][r] * (1.0f / rs[grow]);
        if constexpr (MODE == 2) {
          size_t idx = (size_t)grow * ldc + coloff + gcol;
          v = v > 0.f ? v : (__expf(v) - 1.f);
          Cout[idx] += v;
        } else {
          Cout[(size_t)h * cStride + (size_t)grow * ldc + gcol] = v;
        }
      }
    }
  }
}

// ------------------------------------------------- LN layer 0: LN(x) -> elu -> bf16
__global__ __launch_bounds__(256) void ln0_kernel(const float* __restrict__ xin,
                                                  const float* __restrict__ g,
                                                  const float* __restrict__ b,
                                                  u16* __restrict__ h1b) {
  const int C = 2048;
  int n = blockIdx.x, tid = threadIdx.x;
  __shared__ float red[2][4];
  __shared__ float mrs[2];
  float sum = 0.f, sq = 0.f;
  const float* xr = xin + (size_t)n * C;
  for (int c = tid; c < C; c += 256) {
    float x = xr[c];
    sum += x; sq += x * x;
  }
#pragma unroll
  for (int off = 32; off > 0; off >>= 1) { sum += __shfl_down(sum, off); sq += __shfl_down(sq, off); }
  if ((tid & 63) == 0) { red[0][tid >> 6] = sum; red[1][tid >> 6] = sq; }
  __syncthreads();
  if (tid == 0) {
    float s = red[0][0] + red[0][1] + red[0][2] + red[0][3];
    float q = red[1][0] + red[1][1] + red[1][2] + red[1][3];
    float mean = s / C, var = q / C - mean * mean;
    mrs[0] = mean; mrs[1] = rsqrtf(var + 1e-5f);
  }
  __syncthreads();
  float mean = mrs[0], rstd = mrs[1];
  for (int c = tid; c < C; c += 256) {
    float y = (xr[c] - mean) * rstd * g[c] + b[c];
    float z = y > 0.f ? y : (__expf(y) - 1.f);
    h1b[(size_t)n * C + c] = f2bf(z);
  }
}

// ------------------------------------------------- LN layer 1: mean(4 heads) + rp1 -> LN -> out
__global__ __launch_bounds__(256) void ln1_kernel(const float* __restrict__ hp1,
                                                  const float* __restrict__ rp1,
                                                  const float* __restrict__ g,
                                                  const float* __restrict__ b,
                                                  float* __restrict__ out) {
  const int C = 768;
  int n = blockIdx.x, tid = threadIdx.x;
  __shared__ float xs[768];
  __shared__ float red[2][4];
  __shared__ float mrs[2];
  float sum = 0.f, sq = 0.f;
  for (int c = tid; c < C; c += 256) {
    float x = 0.25f * (hp1[((size_t)0 * NN + n) * C + c] + hp1[((size_t)1 * NN + n) * C + c] +
                       hp1[((size_t)2 * NN + n) * C + c] + hp1[((size_t)3 * NN + n) * C + c]);
    x += rp1[(size_t)n * C + c];     // bias already folded into rp1 by gemm_proj
    xs[c] = x; sum += x; sq += x * x;
  }
#pragma unroll
  for (int off = 32; off > 0; off >>= 1) { sum += __shfl_down(sum, off); sq += __shfl_down(sq, off); }
  if ((tid & 63) == 0) { red[0][tid >> 6] = sum; red[1][tid >> 6] = sq; }
  __syncthreads();
  if (tid == 0) {
    float s = red[0][0] + red[0][1] + red[0][2] + red[0][3];
    float q = red[1][0] + red[1][1] + red[1][2] + red[1][3];
    float mean = s / C, var = q / C - mean * mean;
    mrs[0] = mean; mrs[1] = rsqrtf(var + 1e-5f);
  }
  __syncthreads();
  float mean = mrs[0], rstd = mrs[1];
  for (int c = tid; c < C; c += 256)
    out[(size_t)n * C + c] = (xs[c] - mean) * rstd * g[c] + b[c];
}

// ============================================================================
extern "C" void kernel_launch(void* const* d_in, const int* in_sizes, int n_in,
                              void* d_out, int out_size, void* d_ws, size_t ws_size,
                              hipStream_t stream) {
  (void)in_sizes; (void)n_in; (void)out_size;
  const float* X    = (const float*)d_in[0];
  const int*   adj  = (const int*)d_in[1];
  const float* ew   = (const float*)d_in[2];
  const float* W0   = (const float*)d_in[3];
  const float* a0   = (const float*)d_in[4];
  const float* W1   = (const float*)d_in[5];
  const float* a1   = (const float*)d_in[6];
  const float* rp0w = (const float*)d_in[7];
  const float* rp0b = (const float*)d_in[8];
  const float* rp1w = (const float*)d_in[9];
  const float* rp1b = (const float*)d_in[10];
  const float* ln0g = (const float*)d_in[11];
  const float* ln0b = (const float*)d_in[12];
  const float* ln1g = (const float*)d_in[13];
  const float* ln1b = (const float*)d_in[14];
  float* out = (float*)d_out;
  char* wsb = (char*)d_ws;

  // ---- workspace layout (bytes) ----
  // NOTE: W0T/RP0WT contiguous and W1T/RP1WT contiguous (B-concat for gemm_proj).
  constexpr size_t OFF_XBF   = 0;             // [4096][768]    bf16   6291456
  constexpr size_t OFF_W0T   = 6291456;       // [2048][768]    bf16   3145728  (4 heads x 512)
  constexpr size_t OFF_RP0WT = 9437184;       // [2048][768]    bf16   3145728  (contiguous after W0T)
  constexpr size_t OFF_W1T   = 12582912;      // [3072][2048]   bf16  12582912  (4 heads x 768)
  constexpr size_t OFF_RP1WT = 25165824;      // [768][2048]    bf16   3145728  (contiguous after W1T)
  constexpr size_t OFF_WA0   = 28311552;
  constexpr size_t OFF_WA1   = 28336128;
  constexpr size_t OFF_S0    = 28401664;
  constexpr size_t OFF_S1    = 28532736;
  constexpr size_t OFF_L0    = 28664320;
  constexpr size_t OFF_L1    = 28729856;
  constexpr size_t OFF_H1B   = 28795392;      // [4096][2048] bf16   16777216
  constexpr size_t D         = 45572608;      // dynamic region
  // layer0: WH0T [2048][4096] fp8 @D (8388608);  RP0 [4096][2048] f32 @D+16777216 (33554432)
  // layer1: WH1T [3072][4096] fp8 @D (12582912); RP1 [4096][768]  f32 @D+25165824 (12582912)
  constexpr size_t PD        = D + 50331648;          // P @ 95904256, 4 x 16777216 fp8
  constexpr size_t PN        = (size_t)NN * NN;       // 16777216 per head
  constexpr size_t OFF_HP1   = PD + 4 * PN;           // [4][4096][768] f32 @163013120 -> ends 213344768

  u16*   XBF   = (u16*)(wsb + OFF_XBF);
  u16*   W0T   = (u16*)(wsb + OFF_W0T);
  u16*   RP0WT = (u16*)(wsb + OFF_RP0WT);
  u16*   W1T   = (u16*)(wsb + OFF_W1T);
  u16*   RP1WT = (u16*)(wsb + OFF_RP1WT);
  float* WA0   = (float*)(wsb + OFF_WA0);
  float* WA1   = (float*)(wsb + OFF_WA1);
  float* S0    = (float*)(wsb + OFF_S0);
  float* S1    = (float*)(wsb + OFF_S1);
  float* L0    = (float*)(wsb + OFF_L0);
  float* L1    = (float*)(wsb + OFF_L1);
  u16*   H1B   = (u16*)(wsb + OFF_H1B);
  u8*    WH0T  = (u8*)(wsb + D);
  float* RP0   = (float*)(wsb + D + 16777216);
  u8*    WH1T  = (u8*)(wsb + D);
  float* RP1   = (float*)(wsb + D + 25165824);
  u8*    P     = (u8*)(wsb + PD);
  float* HP1   = (float*)(wsb + OFF_HP1);

  // head-group size from available workspace (ws_size constant per session).
  const int G = (ws_size >= OFF_HP1 + 50331648) ? 4 : 1;

  // ---- prep ----
  cast_f32_bf16<<<dim3((NN * 768 + 255) / 256), 256, 0, stream>>>(X, XBF, NN * 768);
  transcast_f32<<<dim3(16, 24, 4), 256, 0, stream>>>(W0, W0T, 768, 512);
  transcast_f32<<<dim3(24, 64, 4), 256, 0, stream>>>(W1, W1T, 2048, 768);
  transcast_f32<<<dim3(64, 24, 1), 256, 0, stream>>>(rp0w, RP0WT, 768, 2048);
  transcast_f32<<<dim3(24, 64, 1), 256, 0, stream>>>(rp1w, RP1WT, 2048, 768);

  // ---- layer 0 attention scalars (fp32 exact) ----
  wa_kernel<<<dim3(2 * NHEADS * 768 / 4), 256, 0, stream>>>(W0, a0, WA0, 768, 512);
  s_kernel_f32<<<dim3(2 * NHEADS * NN / 4), 256, 0, stream>>>(X, WA0, S0, 768);

  // ---- layer 0: merged projections (Wh0^T fp8 + RP0 fp32+bias), one launch ----
  gemm_proj<<<dim3(32, 32), 256, 0, stream>>>(XBF, W0T, WH0T, RP0, rp0b, 768, 2048, 2048);

  // per head-group: P' then RP0[:, h*512:(h+1)*512] += elu(P' @ Wh0 / l)
  for (int g = 0; g < NHEADS; g += G) {
    if (G == 4) pexp_g_kernel<4><<<dim3(NN), 256, 0, stream>>>(adj, ew, S0, P, L0, g);
    else        pexp_g_kernel<1><<<dim3(NN), 256, 0, stream>>>(adj, ew, S0, P, L0, g);
    gemm_fp8<2><<<dim3(32, 4, G), 256, 0, stream>>>(P, WH0T + (size_t)g * 512 * NN,
        RP0, L0 + (size_t)g * NN, 2048, g * 512, 512, (size_t)512 * NN, 0);
  }
  ln0_kernel<<<dim3(NN), 256, 0, stream>>>(RP0, ln0g, ln0b, H1B);

  // ---- layer 1 attention scalars ----
  wa_kernel<<<dim3(2 * NHEADS * 2048 / 4), 256, 0, stream>>>(W1, a1, WA1, 2048, 768);
  s_kernel_bf16<<<dim3(2 * NHEADS * NN / 4), 256, 0, stream>>>(H1B, WA1, S1, 2048);

  // ---- layer 1: merged projections (Wh1^T fp8 + RP1 fp32+bias), one launch ----
  gemm_proj<<<dim3(32, 30), 256, 0, stream>>>(H1B, W1T, WH1T, RP1, rp1b, 2048, 3072, 768);

  // per head-group: P' then HP1[h] = P' @ Wh1 / l (plain store; ln1 does mean)
  for (int g = 0; g < NHEADS; g += G) {
    if (G == 4) pexp_g_kernel<4><<<dim3(NN), 256, 0, stream>>>(adj, ew, S1, P, L1, g);
    else        pexp_g_kernel<1><<<dim3(NN), 256, 0, stream>>>(adj, ew, S1, P, L1, g);
    gemm_fp8<3><<<dim3(32, 6, G), 256, 0, stream>>>(P, WH1T + (size_t)g * 768 * NN,
        HP1 + (size_t)g * NN * 768, L1 + (size_t)g * NN,
        768, 0, 0, (size_t)768 * NN, (size_t)NN * 768);
  }
  ln1_kernel<<<dim3(NN), 256, 0, stream>>>(HP1, RP1, ln1g, ln1b, out);
}

// Round 7
// 746.690 us; speedup vs baseline: 1.3456x; 1.0849x over previous
//
#include <hip/hip_runtime.h>

// ============================================================================
// KnowledgeGraphEncoder: 2-layer dense GAT, N=4096, H=4.
// bf16 MFMA merged projection GEMMs, BK=64 with XOR-swizzled LDS (conflict-free
// without padding, compatible with global_load_lds);
// fp8(e4m3, per-row-max P) MFMA BK=64 attention GEMMs (b128 K-permute);
// fused 8-way s-kernels; XCD-aware grids. ws ~213 MB.
// ============================================================================

typedef unsigned short u16;
typedef unsigned char u8;
using short8  = __attribute__((ext_vector_type(8))) short;
using float4v = __attribute__((ext_vector_type(4))) float;
using long2v  = __attribute__((ext_vector_type(2))) long;

#define NN 4096
#define NHEADS 4

__device__ __forceinline__ u16 f2bf(float f) {
  union { float f; unsigned u; } v; v.f = f;
  unsigned u = v.u;
  return (u16)((u + 0x7FFFu + ((u >> 16) & 1u)) >> 16);   // RNE
}
__device__ __forceinline__ float bf2f(u16 x) {
  union { unsigned u; float f; } v; v.u = ((unsigned)x) << 16; return v.f;
}
// pack 4 floats -> 4 fp8 e4m3 bytes (HW cvt, OCP on gfx950)
__device__ __forceinline__ unsigned pk_fp8x4(float a, float b, float c, float d) {
  int lo = __builtin_amdgcn_cvt_pk_fp8_f32(a, b, 0, false);
  return (unsigned)__builtin_amdgcn_cvt_pk_fp8_f32(c, d, lo, true);
}

// async global->LDS, 16B per lane, LDS dest = wave-uniform base + lane*16
__device__ __forceinline__ void async16(const void* g, void* l) {
  __builtin_amdgcn_global_load_lds(
      (const __attribute__((address_space(1))) unsigned int*)g,
      (__attribute__((address_space(3))) unsigned int*)l, 16, 0, 0);
}

// ---------------------------------------------------------------- cast fp32->bf16
__global__ __launch_bounds__(256) void cast_f32_bf16(const float* __restrict__ in,
                                                     u16* __restrict__ out, int n) {
  int i = blockIdx.x * 256 + threadIdx.x;
  if (i < n) out[i] = f2bf(in[i]);
}

// ------------------------------------------------- transpose+cast fp32 -> bf16
// in [z][R][C] -> out [z][C][R]
__global__ __launch_bounds__(256) void transcast_f32(const float* __restrict__ in,
                                                     u16* __restrict__ out, int R, int C) {
  __shared__ float t[32][33];
  size_t zoff = (size_t)blockIdx.z * R * C;
  in += zoff; out += zoff;
  int c0 = blockIdx.x * 32, r0 = blockIdx.y * 32;
  int tx = threadIdx.x & 31, ty = threadIdx.x >> 5;
#pragma unroll
  for (int i = 0; i < 32; i += 8)
    t[ty + i][tx] = in[(size_t)(r0 + ty + i) * C + (c0 + tx)];
  __syncthreads();
#pragma unroll
  for (int i = 0; i < 32; i += 8)
    out[(size_t)(c0 + ty + i) * R + (r0 + tx)] = f2bf(t[tx][ty + i]);
}

// ------------------------------------------------- wa[side][h][f] = sum_o W[h][f][o]*a[h][side*O+o]
__global__ __launch_bounds__(256) void wa_kernel(const float* __restrict__ W,
                                                 const float* __restrict__ a,
                                                 float* __restrict__ wa, int F, int O) {
  int gw = blockIdx.x * 4 + (threadIdx.x >> 6);
  int lane = threadIdx.x & 63;
  int total = 2 * NHEADS * F;
  if (gw >= total) return;
  int side = gw / (NHEADS * F);
  int rem = gw - side * NHEADS * F;
  int h = rem / F, f = rem - h * F;
  const float* wrow = W + ((size_t)h * F + f) * O;
  const float* av = a + (size_t)h * 2 * O + (size_t)side * O;
  float s = 0.f;
  for (int o = lane; o < O; o += 64) s += wrow[o] * av[o];
#pragma unroll
  for (int off = 32; off > 0; off >>= 1) s += __shfl_down(s, off);
  if (lane == 0) wa[gw] = s;
}

// ------------------------------------------------- fused 8-way s: one wave per node
// sout[k][n] = sum_f X[n][f] * wa[k][f], k = side*4+h in 0..7
__global__ __launch_bounds__(256) void s8_kernel_f32(const float* __restrict__ X,
                                                     const float* __restrict__ wa,
                                                     float* __restrict__ sout, int F) {
  int n = blockIdx.x * 4 + (threadIdx.x >> 6);
  int lane = threadIdx.x & 63;
  const float* x = X + (size_t)n * F;
  float acc[8] = {};
  for (int f = lane; f < F; f += 64) {
    float xv = x[f];
#pragma unroll
    for (int k = 0; k < 8; k++) acc[k] += xv * wa[(size_t)k * F + f];
  }
#pragma unroll
  for (int k = 0; k < 8; k++) {
    float s = acc[k];
#pragma unroll
    for (int off = 32; off > 0; off >>= 1) s += __shfl_down(s, off);
    if (lane == 0) sout[(size_t)k * NN + n] = s;
  }
}

__global__ __launch_bounds__(256) void s8_kernel_bf16(const u16* __restrict__ X,
                                                      const float* __restrict__ wa,
                                                      float* __restrict__ sout, int F) {
  int n = blockIdx.x * 4 + (threadIdx.x >> 6);
  int lane = threadIdx.x & 63;
  const u16* x = X + (size_t)n * F;
  float acc[8] = {};
  for (int f = lane; f < F; f += 64) {
    float xv = bf2f(x[f]);
#pragma unroll
    for (int k = 0; k < 8; k++) acc[k] += xv * wa[(size_t)k * F + f];
  }
#pragma unroll
  for (int k = 0; k < 8; k++) {
    float s = acc[k];
#pragma unroll
    for (int off = 32; off > 0; off >>= 1) s += __shfl_down(s, off);
    if (lane == 0) sout[(size_t)k * NN + n] = s;
  }
}

// ------------------------------------------------- G-head P' = exp(v - rowmax) fp8, l = rowsum (fp32)
template <int G>
__global__ __launch_bounds__(256) void pexp_g_kernel(const int* __restrict__ adj,
                                                     const float* __restrict__ ew,
                                                     const float* __restrict__ s,
                                                     u8* __restrict__ P,
                                                     float* __restrict__ L, int hb) {
  __shared__ float vbuf[G][NN];
  __shared__ float mred[G][4];
  __shared__ float lred[G][4];
  __shared__ float mrow[G];
  int i = blockIdx.x, tid = threadIdx.x;
  float sr[G], mx[G], lacc[G];
#pragma unroll
  for (int z = 0; z < G; z++) {
    sr[z] = s[(size_t)(hb + z) * NN + i];
    mx[z] = -3e38f;
    lacc[z] = 0.f;
  }
  const int4* arow = (const int4*)(adj + (size_t)i * NN);
  const float4* wrow = (const float4*)(ew + (size_t)i * NN);
  // pass 1: v -> LDS, row max
  for (int jv = tid; jv < NN / 4; jv += 256) {
    int4 a = arow[jv];
    float4 w = wrow[jv];
    int j0 = jv * 4;
    float we[4]; we[0] = w.x; we[1] = w.y; we[2] = w.z; we[3] = w.w;
    bool m[4];
    m[0] = (a.x != 0) || (j0 + 0 == i);
    m[1] = (a.y != 0) || (j0 + 1 == i);
    m[2] = (a.z != 0) || (j0 + 2 == i);
    m[3] = (a.w != 0) || (j0 + 3 == i);
#pragma unroll
    for (int z = 0; z < G; z++) {
      const float4 sd4 = *(const float4*)(s + (size_t)(NHEADS + hb + z) * NN + j0);
      float sd[4]; sd[0] = sd4.x; sd[1] = sd4.y; sd[2] = sd4.z; sd[3] = sd4.w;
      float4 vv;
      float* vp = (float*)&vv;
#pragma unroll
      for (int k = 0; k < 4; k++) {
        float x = sr[z] + sd[k];
        float e = x > 0.f ? x : 0.2f * x;
        float v = (m[k] ? e : -9e15f) * we[k];
        vp[k] = v;
        mx[z] = fmaxf(mx[z], v);
      }
      *(float4*)(&vbuf[z][j0]) = vv;
    }
  }
#pragma unroll
  for (int z = 0; z < G; z++) {
    float r = mx[z];
#pragma unroll
    for (int off = 32; off > 0; off >>= 1) r = fmaxf(r, __shfl_down(r, off));
    if ((tid & 63) == 0) mred[z][tid >> 6] = r;
  }
  __syncthreads();
  if (tid < G)
    mrow[tid] = fmaxf(fmaxf(mred[tid][0], mred[tid][1]), fmaxf(mred[tid][2], mred[tid][3]));
  __syncthreads();
  float mv[G];
#pragma unroll
  for (int z = 0; z < G; z++) mv[z] = mrow[z];
  // pass 2: p = exp(v - m), fp8 pack, rowsum
  for (int jv = tid; jv < NN / 4; jv += 256) {
    int j0 = jv * 4;
#pragma unroll
    for (int z = 0; z < G; z++) {
      float4 vv = *(const float4*)(&vbuf[z][j0]);
      float p0 = __expf(vv.x - mv[z]);
      float p1 = __expf(vv.y - mv[z]);
      float p2 = __expf(vv.z - mv[z]);
      float p3 = __expf(vv.w - mv[z]);
      lacc[z] += (p0 + p1) + (p2 + p3);
      *(unsigned*)(P + ((size_t)z * NN + i) * NN + j0) = pk_fp8x4(p0, p1, p2, p3);
    }
  }
#pragma unroll
  for (int z = 0; z < G; z++) {
    float r = lacc[z];
#pragma unroll
    for (int off = 32; off > 0; off >>= 1) r += __shfl_down(r, off);
    if ((tid & 63) == 0) lred[z][tid >> 6] = r;
  }
  __syncthreads();
  if (tid < G)
    L[(size_t)(hb + tid) * NN + i] = lred[tid][0] + lred[tid][1] + lred[tid][2] + lred[tid][3];
}

// ------------------------------------------------- merged projection GEMM (bf16, BK=64, XOR swizzle)
// LDS[r][c] (16B chunks, c=0..7) holds global chunk (c ^ (r&7)); fragment reads
// chunk (q ^ (r&7)) / ((4+q) ^ (r&7)) -> standard K-order, conflict-free banks.
// col0 <  split: fp8 TRANSPOSED store into F8T[gcol][0..4095]   (Wh^T, packed dword)
// col0 >= split: fp32 store F32[grow][gcol-split] = v + bias[gcol-split]
// Grid: (x = 32 row panels, y = col panels). XCD: same-A -> same XCD.
__global__ __launch_bounds__(256) void gemm_proj(const u16* __restrict__ A,
                                                 const u16* __restrict__ Bt,
                                                 u8* __restrict__ F8T,
                                                 float* __restrict__ F32,
                                                 const float* __restrict__ bias,
                                                 int K, int split, int ldcF) {
  int row0 = blockIdx.x * 128;
  int col0 = blockIdx.y * 128;

  __shared__ u16 ldsA[128 * 64];
  __shared__ u16 ldsB[128 * 64];

  int tid = threadIdx.x;
  int wave = tid >> 6, lane = tid & 63;
  int wm = wave >> 1, wn = wave & 1;
  int lm = lane & 15, quad = lane >> 4;

  // staging map: row sr = tid>>3 (0..31, +32 per batch), chunk sc = tid&7
  int sr = tid >> 3, sc = tid & 7;
  int scg = sc ^ (sr & 7);                       // fetch swizzled global chunk
  const u16* aPtr = A  + (size_t)(row0 + sr) * K + scg * 8;
  const u16* bPtr = Bt + (size_t)(col0 + sr) * K + scg * 8;
  u16* ldsAw = &ldsA[wave * 512];                // wave-uniform dest (1024 B/wave)
  u16* ldsBw = &ldsB[wave * 512];
  const size_t rowStep = (size_t)32 * K;

  float4v acc[4][4] = {};

  for (int k0 = 0; k0 < K; k0 += 64) {
    __syncthreads();
#pragma unroll
    for (int b = 0; b < 4; b++) {
      async16(aPtr + k0 + b * rowStep, ldsAw + b * 2048);
      async16(bPtr + k0 + b * rowStep, ldsBw + b * 2048);
    }
    __syncthreads();
    short8 af[4][2], bf[4][2];
#pragma unroll
    for (int s = 0; s < 4; s++) {
      int ra = wm * 64 + s * 16 + lm;
      int rb = wn * 64 + s * 16 + lm;
      int swa = ra & 7, swb = rb & 7;
      af[s][0] = *(const short8*)(&ldsA[ra * 64 + ((quad ^ swa) * 8)]);
      af[s][1] = *(const short8*)(&ldsA[ra * 64 + (((4 + quad) ^ swa) * 8)]);
      bf[s][0] = *(const short8*)(&ldsB[rb * 64 + ((quad ^ swb) * 8)]);
      bf[s][1] = *(const short8*)(&ldsB[rb * 64 + (((4 + quad) ^ swb) * 8)]);
    }
#pragma unroll
    for (int i = 0; i < 4; i++)
#pragma unroll
      for (int j = 0; j < 4; j++) {
        acc[i][j] = __builtin_amdgcn_mfma_f32_16x16x32_bf16(af[i][0], bf[j][0], acc[i][j], 0, 0, 0);
        acc[i][j] = __builtin_amdgcn_mfma_f32_16x16x32_bf16(af[i][1], bf[j][1], acc[i][j], 0, 0, 0);
      }
  }

  if (col0 < split) {
#pragma unroll
    for (int i = 0; i < 4; i++) {
#pragma unroll
      for (int j = 0; j < 4; j++) {
        int grow0 = row0 + wm * 64 + i * 16 + (lane >> 4) * 4;
        int gcol = col0 + wn * 64 + j * 16 + lm;
        unsigned pk = pk_fp8x4(acc[i][j][0], acc[i][j][1], acc[i][j][2], acc[i][j][3]);
        *(unsigned*)&F8T[(size_t)gcol * NN + grow0] = pk;
      }
    }
  } else {
#pragma unroll
    for (int i = 0; i < 4; i++) {
#pragma unroll
      for (int j = 0; j < 4; j++) {
#pragma unroll
        for (int r = 0; r < 4; r++) {
          int grow = row0 + wm * 64 + i * 16 + (lane >> 4) * 4 + r;
          int gcol = col0 + wn * 64 + j * 16 + lm - split;
          F32[(size_t)grow * ldcF + gcol] = acc[i][j][r] + bias[gcol];
        }
      }
    }
  }
}

// ------------------------------------------------- 128x128 fp8 MFMA GEMM, BK=64, B^T input, K=NN
// ds_read_b128 fragment loads via K-permutation (conflict-free LDS).
// MODE 2: C[grow*ldc + coloff+gcol] += elu(v / l[row])   (layer-0 attn, disjoint head cols)
// MODE 3: C[h*cStride + grow*ldc + gcol] = v / l[row]    (layer-1 attn, per-head plain store)
// Grid: (x = 32 row panels, y = col panels, z = heads in group).
template <int MODE>
__global__ __launch_bounds__(256) void gemm_fp8(const u8* __restrict__ A,
                                                const u8* __restrict__ Bt,
                                                float* __restrict__ Cout,
                                                const float* __restrict__ rowscale,
                                                int ldc, int coloff_base, int coloff_step,
                                                size_t bStride, size_t cStride) {
  constexpr int K = NN;
  int h = blockIdx.z;
  const u8* Ab = A + (size_t)h * ((size_t)NN * NN);
  const u8* Bb = Bt + (size_t)h * bStride;
  const float* rs = rowscale + (size_t)h * NN;
  int row0 = blockIdx.x * 128;
  int col0 = blockIdx.y * 128;
  int coloff = coloff_base + h * coloff_step;

  __shared__ u8 ldsA[128 * 64];
  __shared__ u8 ldsB[128 * 64];

  int tid = threadIdx.x;
  int wave = tid >> 6, lane = tid & 63;
  int wm = wave >> 1, wn = wave & 1;
  int lm = lane & 15, q16 = (lane >> 4) * 16;

  const u8* aPtr = Ab + (size_t)(row0 + (tid >> 2)) * K + ((tid & 3) * 16);
  const u8* bPtr = Bb + (size_t)(col0 + (tid >> 2)) * K + ((tid & 3) * 16);
  u8* ldsAw = &ldsA[wave * 1024];
  u8* ldsBw = &ldsB[wave * 1024];
  const size_t rowStep = (size_t)64 * K;

  float4v acc[4][4] = {};

  for (int k0 = 0; k0 < K; k0 += 64) {
    __syncthreads();
    async16(aPtr + k0,           ldsAw);           // rows 0-63
    async16(aPtr + k0 + rowStep, ldsAw + 4096);    // rows 64-127
    async16(bPtr + k0,           ldsBw);
    async16(bPtr + k0 + rowStep, ldsBw + 4096);
    __syncthreads();
    long2v a16[4], b16[4];
#pragma unroll
    for (int s = 0; s < 4; s++) {
      a16[s] = *(const long2v*)(&ldsA[(wm * 64 + s * 16 + lm) * 64 + q16]);
      b16[s] = *(const long2v*)(&ldsB[(wn * 64 + s * 16 + lm) * 64 + q16]);
    }
#pragma unroll
    for (int i = 0; i < 4; i++)
#pragma unroll
      for (int j = 0; j < 4; j++) {
        acc[i][j] = __builtin_amdgcn_mfma_f32_16x16x32_fp8_fp8(a16[i][0], b16[j][0], acc[i][j], 0, 0, 0);
        acc[i][j] = __builtin_amdgcn_mfma_f32_16x16x32_fp8_fp8(a16[i][1], b16[j][1], acc[i][j], 0, 0, 0);
      }
  }

#pragma unroll
  for (int i = 0; i < 4; i++) {
#pragma unroll
    for (int j = 0; j < 4; j++) {
#pragma unroll
      for (int r = 0; r < 4; r++) {
        int grow = row0 + wm * 64 + i * 16 + (lane >> 4) * 4 + r;
        int gcol = col0 + wn * 64 + j * 16 + lm;
        float v = acc[i][j][r] * (1.0f / rs[grow]);
        if constexpr (MODE == 2) {
          size_t idx = (size_t)grow * ldc + coloff + gcol;
          v = v > 0.f ? v : (__expf(v) - 1.f);
          Cout[idx] += v;
        } else {
          Cout[(size_t)h * cStride + (size_t)grow * ldc + gcol] = v;
        }
      }
    }
  }
}

// ------------------------------------------------- LN layer 0: LN(x) -> elu -> bf16
__global__ __launch_bounds__(256) void ln0_kernel(const float* __restrict__ xin,
                                                  const float* __restrict__ g,
                                                  const float* __restrict__ b,
                                                  u16* __restrict__ h1b) {
  const int C = 2048;
  int n = blockIdx.x, tid = threadIdx.x;
  __shared__ float red[2][4];
  __shared__ float mrs[2];
  float sum = 0.f, sq = 0.f;
  const float* xr = xin + (size_t)n * C;
  for (int c = tid; c < C; c += 256) {
    float x = xr[c];
    sum += x; sq += x * x;
  }
#pragma unroll
  for (int off = 32; off > 0; off >>= 1) { sum += __shfl_down(sum, off); sq += __shfl_down(sq, off); }
  if ((tid & 63) == 0) { red[0][tid >> 6] = sum; red[1][tid >> 6] = sq; }
  __syncthreads();
  if (tid == 0) {
    float s = red[0][0] + red[0][1] + red[0][2] + red[0][3];
    float q = red[1][0] + red[1][1] + red[1][2] + red[1][3];
    float mean = s / C, var = q / C - mean * mean;
    mrs[0] = mean; mrs[1] = rsqrtf(var + 1e-5f);
  }
  __syncthreads();
  float mean = mrs[0], rstd = mrs[1];
  for (int c = tid; c < C; c += 256) {
    float y = (xr[c] - mean) * rstd * g[c] + b[c];
    float z = y > 0.f ? y : (__expf(y) - 1.f);
    h1b[(size_t)n * C + c] = f2bf(z);
  }
}

// ------------------------------------------------- LN layer 1: mean(4 heads) + rp1 -> LN -> out
__global__ __launch_bounds__(256) void ln1_kernel(const float* __restrict__ hp1,
                                                  const float* __restrict__ rp1,
                                                  const float* __restrict__ g,
                                                  const float* __restrict__ b,
                                                  float* __restrict__ out) {
  const int C = 768;
  int n = blockIdx.x, tid = threadIdx.x;
  __shared__ float xs[768];
  __shared__ float red[2][4];
  __shared__ float mrs[2];
  float sum = 0.f, sq = 0.f;
  for (int c = tid; c < C; c += 256) {
    float x = 0.25f * (hp1[((size_t)0 * NN + n) * C + c] + hp1[((size_t)1 * NN + n) * C + c] +
                       hp1[((size_t)2 * NN + n) * C + c] + hp1[((size_t)3 * NN + n) * C + c]);
    x += rp1[(size_t)n * C + c];     // bias already folded into rp1 by gemm_proj
    xs[c] = x; sum += x; sq += x * x;
  }
#pragma unroll
  for (int off = 32; off > 0; off >>= 1) { sum += __shfl_down(sum, off); sq += __shfl_down(sq, off); }
  if ((tid & 63) == 0) { red[0][tid >> 6] = sum; red[1][tid >> 6] = sq; }
  __syncthreads();
  if (tid == 0) {
    float s = red[0][0] + red[0][1] + red[0][2] + red[0][3];
    float q = red[1][0] + red[1][1] + red[1][2] + red[1][3];
    float mean = s / C, var = q / C - mean * mean;
    mrs[0] = mean; mrs[1] = rsqrtf(var + 1e-5f);
  }
  __syncthreads();
  float mean = mrs[0], rstd = mrs[1];
  for (int c = tid; c < C; c += 256)
    out[(size_t)n * C + c] = (xs[c] - mean) * rstd * g[c] + b[c];
}

// ============================================================================
extern "C" void kernel_launch(void* const* d_in, const int* in_sizes, int n_in,
                              void* d_out, int out_size, void* d_ws, size_t ws_size,
                              hipStream_t stream) {
  (void)in_sizes; (void)n_in; (void)out_size;
  const float* X    = (const float*)d_in[0];
  const int*   adj  = (const int*)d_in[1];
  const float* ew   = (const float*)d_in[2];
  const float* W0   = (const float*)d_in[3];
  const float* a0   = (const float*)d_in[4];
  const float* W1   = (const float*)d_in[5];
  const float* a1   = (const float*)d_in[6];
  const float* rp0w = (const float*)d_in[7];
  const float* rp0b = (const float*)d_in[8];
  const float* rp1w = (const float*)d_in[9];
  const float* rp1b = (const float*)d_in[10];
  const float* ln0g = (const float*)d_in[11];
  const float* ln0b = (const float*)d_in[12];
  const float* ln1g = (const float*)d_in[13];
  const float* ln1b = (const float*)d_in[14];
  float* out = (float*)d_out;
  char* wsb = (char*)d_ws;

  // ---- workspace layout (bytes) ----
  // NOTE: W0T/RP0WT contiguous and W1T/RP1WT contiguous (B-concat for gemm_proj).
  constexpr size_t OFF_XBF   = 0;             // [4096][768]    bf16   6291456
  constexpr size_t OFF_W0T   = 6291456;       // [2048][768]    bf16   3145728  (4 heads x 512)
  constexpr size_t OFF_RP0WT = 9437184;       // [2048][768]    bf16   3145728  (contiguous after W0T)
  constexpr size_t OFF_W1T   = 12582912;      // [3072][2048]   bf16  12582912  (4 heads x 768)
  constexpr size_t OFF_RP1WT = 25165824;      // [768][2048]    bf16   3145728  (contiguous after W1T)
  constexpr size_t OFF_WA0   = 28311552;
  constexpr size_t OFF_WA1   = 28336128;
  constexpr size_t OFF_S0    = 28401664;
  constexpr size_t OFF_S1    = 28532736;
  constexpr size_t OFF_L0    = 28664320;
  constexpr size_t OFF_L1    = 28729856;
  constexpr size_t OFF_H1B   = 28795392;      // [4096][2048] bf16   16777216
  constexpr size_t D         = 45572608;      // dynamic region
  // layer0: WH0T [2048][4096] fp8 @D (8388608);  RP0 [4096][2048] f32 @D+16777216 (33554432)
  // layer1: WH1T [3072][4096] fp8 @D (12582912); RP1 [4096][768]  f32 @D+25165824 (12582912)
  constexpr size_t PD        = D + 50331648;          // P @ 95904256, 4 x 16777216 fp8
  constexpr size_t PN        = (size_t)NN * NN;       // 16777216 per head
  constexpr size_t OFF_HP1   = PD + 4 * PN;           // [4][4096][768] f32 @163013120 -> ends 213344768

  u16*   XBF   = (u16*)(wsb + OFF_XBF);
  u16*   W0T   = (u16*)(wsb + OFF_W0T);
  u16*   RP0WT = (u16*)(wsb + OFF_RP0WT);
  u16*   W1T   = (u16*)(wsb + OFF_W1T);
  u16*   RP1WT = (u16*)(wsb + OFF_RP1WT);
  float* WA0   = (float*)(wsb + OFF_WA0);
  float* WA1   = (float*)(wsb + OFF_WA1);
  float* S0    = (float*)(wsb + OFF_S0);
  float* S1    = (float*)(wsb + OFF_S1);
  float* L0    = (float*)(wsb + OFF_L0);
  float* L1    = (float*)(wsb + OFF_L1);
  u16*   H1B   = (u16*)(wsb + OFF_H1B);
  u8*    WH0T  = (u8*)(wsb + D);
  float* RP0   = (float*)(wsb + D + 16777216);
  u8*    WH1T  = (u8*)(wsb + D);
  float* RP1   = (float*)(wsb + D + 25165824);
  u8*    P     = (u8*)(wsb + PD);
  float* HP1   = (float*)(wsb + OFF_HP1);

  // head-group size from available workspace (ws_size constant per session).
  const int G = (ws_size >= OFF_HP1 + 50331648) ? 4 : 1;

  // ---- prep ----
  cast_f32_bf16<<<dim3((NN * 768 + 255) / 256), 256, 0, stream>>>(X, XBF, NN * 768);
  transcast_f32<<<dim3(16, 24, 4), 256, 0, stream>>>(W0, W0T, 768, 512);
  transcast_f32<<<dim3(24, 64, 4), 256, 0, stream>>>(W1, W1T, 2048, 768);
  transcast_f32<<<dim3(64, 24, 1), 256, 0, stream>>>(rp0w, RP0WT, 768, 2048);
  transcast_f32<<<dim3(24, 64, 1), 256, 0, stream>>>(rp1w, RP1WT, 2048, 768);

  // ---- layer 0 attention scalars (fp32 exact) ----
  wa_kernel<<<dim3(2 * NHEADS * 768 / 4), 256, 0, stream>>>(W0, a0, WA0, 768, 512);
  s8_kernel_f32<<<dim3(NN / 4), 256, 0, stream>>>(X, WA0, S0, 768);

  // ---- layer 0: merged projections (Wh0^T fp8 + RP0 fp32+bias), one launch ----
  gemm_proj<<<dim3(32, 32), 256, 0, stream>>>(XBF, W0T, WH0T, RP0, rp0b, 768, 2048, 2048);

  // per head-group: P' then RP0[:, h*512:(h+1)*512] += elu(P' @ Wh0 / l)
  for (int g = 0; g < NHEADS; g += G) {
    if (G == 4) pexp_g_kernel<4><<<dim3(NN), 256, 0, stream>>>(adj, ew, S0, P, L0, g);
    else        pexp_g_kernel<1><<<dim3(NN), 256, 0, stream>>>(adj, ew, S0, P, L0, g);
    gemm_fp8<2><<<dim3(32, 4, G), 256, 0, stream>>>(P, WH0T + (size_t)g * 512 * NN,
        RP0, L0 + (size_t)g * NN, 2048, g * 512, 512, (size_t)512 * NN, 0);
  }
  ln0_kernel<<<dim3(NN), 256, 0, stream>>>(RP0, ln0g, ln0b, H1B);

  // ---- layer 1 attention scalars ----
  wa_kernel<<<dim3(2 * NHEADS * 2048 / 4), 256, 0, stream>>>(W1, a1, WA1, 2048, 768);
  s8_kernel_bf16<<<dim3(NN / 4), 256, 0, stream>>>(H1B, WA1, S1, 2048);

  // ---- layer 1: merged projections (Wh1^T fp8 + RP1 fp32+bias), one launch ----
  gemm_proj<<<dim3(32, 30), 256, 0, stream>>>(H1B, W1T, WH1T, RP1, rp1b, 2048, 3072, 768);

  // per head-group: P' then HP1[h] = P' @ Wh1 / l (plain store; ln1 does mean)
  for (int g = 0; g < NHEADS; g += G) {
    if (G == 4) pexp_g_kernel<4><<<dim3(NN), 256, 0, stream>>>(adj, ew, S1, P, L1, g);
    else        pexp_g_kernel<1><<<dim3(NN), 256, 0, stream>>>(adj, ew, S1, P, L1, g);
    gemm_fp8<3><<<dim3(32, 6, G), 256, 0, stream>>>(P, WH1T + (size_t)g * 768 * NN,
        HP1 + (size_t)g * NN * 768, L1 + (size_t)g * NN,
        768, 0, 0, (size_t)768 * NN, (size_t)NN * 768);
  }
  ln1_kernel<<<dim3(NN), 256, 0, stream>>>(HP1, RP1, ln1g, ln1b, out);
}